// Round 3
// baseline (34967.105 us; speedup 1.0000x reference)
//
#include <hip/hip_runtime.h>
#include <math.h>

#define Hn 1024
#define Gn 4096   // 4*H
#define Bn 64
#define Tn 512
#define Vn 128
#define NWG 196
#define NPH 515       // phases: H0 t=p<512, X1 t=p-1, H1 t=p-2, C t=p-3
#define HSLOT 131072  // ushorts per h-fragment slot: 64ks x 2pl x 2mt x 64lane x 8e

typedef short bf16x8 __attribute__((ext_vector_type(8)));
typedef float f32x16 __attribute__((ext_vector_type(16)));

#define MFMA(a, b, c) __builtin_amdgcn_mfma_f32_32x32x16_bf16(a, b, c, 0, 0, 0)

// ---------------- numeric helpers ----------------
__device__ __forceinline__ unsigned short bf_hi(float x) {
  unsigned u = __builtin_bit_cast(unsigned, x);
  return (unsigned short)((u + 0x7fffu + ((u >> 16) & 1u)) >> 16);  // RNE bf16
}
__device__ __forceinline__ float bf_f(unsigned short h) {
  unsigned u = ((unsigned)h) << 16;
  return __builtin_bit_cast(float, u);
}
__device__ __forceinline__ float sigf(float x) {
  float e = exp2f(x * -1.442695040888963f);
  return __fdividef(1.f, 1.f + e);
}
__device__ __forceinline__ float tanh_(float x) {
  x = fminf(fmaxf(x, -15.f), 15.f);
  float e = exp2f(x * -2.885390081777926f);
  return __fdividef(1.f - e, 1.f + e);
}

// ---------------- EW0 = embed @ Wx0 + b0  (V x G), fp32 (round-2 verified) ----------------
__global__ void ew0_kernel(const float* __restrict__ embed, const float* __restrict__ Wx0,
                           const float* __restrict__ bias, float* __restrict__ EW0) {
  int n = blockIdx.x * 256 + threadIdx.x;
  int vb = blockIdx.y * 8;
  float acc[8] = {0, 0, 0, 0, 0, 0, 0, 0};
  for (int k = 0; k < Hn; k++) {
    float w = Wx0[(size_t)k * Gn + n];
#pragma unroll
    for (int i = 0; i < 8; i++)
      acc[i] = fmaf(embed[(vb + i) * Hn + k], w, acc[i]);
  }
  float bb = bias[n];
#pragma unroll
  for (int i = 0; i < 8; i++)
    EW0[(size_t)(vb + i) * Gn + n] = acc[i] + bb;
}

// ---------------- grid barrier (sense via monotone flag) ----------------
__device__ __forceinline__ void gridbar(unsigned* cnt, unsigned* flag, int p) {
  __threadfence();   // release: flush this CU/XCD's writes toward coherent point
  __syncthreads();
  if (threadIdx.x == 0) {
    unsigned old = atomicAdd(cnt, 1u);
    if (old == (unsigned)(NWG - 1)) {
      atomicExch(cnt, 0u);
      __threadfence();
      atomicExch(flag, (unsigned)(p + 1));
    } else {
      while (atomicAdd(flag, 0u) < (unsigned)(p + 1)) __builtin_amdgcn_s_sleep(2);
    }
    __threadfence(); // acquire: invalidate L1/L2 so fresh remote data is visible
  }
  __syncthreads();
}

// ---------------- split-2 GEMM inner loop ----------------
// A-frag layout (global): [ks][pl][mt][lane64][8e] ushort. LDS wlo: [nt][64ks][lane64][8e].
template <int NKS>
__device__ __forceinline__ f32x16 gemm_run(const unsigned short* __restrict__ A,
                                           const unsigned short* wlo,
                                           const bf16x8 (&whi)[32],
                                           int ks0, int ntv, int mtv, int l) {
  f32x16 acc = {};
#pragma unroll
  for (int k2 = 0; k2 < NKS; ++k2) {
    int ks = ks0 + k2;
    bf16x8 ahi = *(const bf16x8*)(A + (((size_t)ks * 2 + 0) * 2 + mtv) * 512 + (size_t)l * 8);
    bf16x8 alo = *(const bf16x8*)(A + (((size_t)ks * 2 + 1) * 2 + mtv) * 512 + (size_t)l * 8);
    bf16x8 blo = *(const bf16x8*)(wlo + ((size_t)ntv * 64 + ks) * 512 + (size_t)l * 8);
    acc = MFMA(ahi, whi[k2], acc);  // hi*hi
    acc = MFMA(alo, whi[k2], acc);  // lo*hi
    acc = MFMA(ahi, blo, acc);      // hi*lo
  }
  return acc;
}

// ---------------- persistent phase-pipelined kernel ----------------
// blocks: [0,64) H0 (Wh0, layer0 recurrent+update), [64,128) X1 (Wx1 partials),
//         [128,192) H1 (Wh1 + P combine + update), [192,196) C (out-proj).
// LDS: wlo 131072B | xg 17408B (reduce slots / gate buf [64][68]) | cb 4096B (c-state)
__global__ __launch_bounds__(512, 2)
void persist_kernel(const int* __restrict__ idx,
                    const float* __restrict__ Wx, const float* __restrict__ Wh,
                    const float* __restrict__ bias, const float* __restrict__ Wout,
                    const float* __restrict__ EW0,
                    unsigned short* __restrict__ h0f, unsigned short* __restrict__ h1f,
                    float* __restrict__ P, float* __restrict__ out,
                    unsigned* __restrict__ bar) {
  extern __shared__ char smem[];
  unsigned short* wlo = (unsigned short*)smem;
  float* xg = (float*)(smem + 131072);
  float* cb = (float*)(smem + 131072 + 17408);

  const int b = blockIdx.x, tid = threadIdx.x;
  const int wv = tid >> 6, l = tid & 63;
  const int type = (b < 64) ? 0 : (b < 128) ? 1 : (b < 192) ? 2 : 3;
  const int i = b - ((type == 0) ? 0 : (type == 1) ? 64 : (type == 2) ? 128 : 192);

  const int mtv = wv & 1;
  const int ntv = (type == 3) ? 0 : ((wv >> 1) & 1);
  const int khv = (type == 3) ? (wv >> 1) : (wv >> 2);
  const int ks0 = khv * ((type == 3) ? 16 : 32);

  // ---- one-time: pack this WG's weight slice (hi -> VGPRs, lo -> LDS) ----
  const float* Wsrc;
  int stride, colv;
  if (type == 3) {
    Wsrc = Wout; stride = Vn; colv = 32 * i + (l & 31);
  } else {
    Wsrc = (type == 0) ? Wh : (type == 1) ? (Wx + (size_t)Hn * Gn) : (Wh + (size_t)Hn * Gn);
    stride = Gn;
    int c32 = l & 31;
    colv = (c32 >> 3) * Hn + 16 * i + ntv * 8 + (c32 & 7);
  }
  const int o8 = l >> 5;
  const int nks = (type == 3) ? 16 : 32;
  bf16x8 whi[32];
#pragma unroll
  for (int k2 = 0; k2 < 32; ++k2) {
    if (k2 < nks) {
      int ks = ks0 + k2;
      bf16x8 hv, lv;
#pragma unroll
      for (int e = 0; e < 8; ++e) {
        int k = ks * 16 + o8 * 8 + e;
        float w = Wsrc[(size_t)k * stride + colv];
        unsigned short h = bf_hi(w);
        unsigned short lo = bf_hi(w - bf_f(h));
        hv[e] = (short)h; lv[e] = (short)lo;
      }
      whi[k2] = hv;
      *(bf16x8*)(wlo + ((size_t)ntv * 64 + ks) * 512 + (size_t)l * 8) = lv;
    }
  }
  for (int q = tid; q < 1024; q += 512) cb[q] = 0.f;  // c-state [16j][64b]
  __syncthreads();

  unsigned* cnt = bar;
  unsigned* flag = bar + 64;

  // ---- phase loop ----
  for (int p = 0; p < NPH; ++p) {
    const int sA = (p + 1) & 1;  // all consumers read slot (p-1)&1 == (p+1)&1 resp. (p-3)&1
    int t; bool active;
    if (type == 0)      { t = p;     active = (t < Tn); }
    else if (type == 1) { t = p - 1; active = (t >= 0 && t < Tn); }
    else if (type == 2) { t = p - 2; active = (t >= 0 && t < Tn); }
    else                { t = p - 3; active = (t >= 0 && t < Tn); }

    if (active) {
      const unsigned short* Asrc =
          ((type <= 1) ? h0f : h1f) + (size_t)sA * HSLOT;

      if (type < 3) {
        f32x16 acc = gemm_run<32>(Asrc, wlo, whi, ks0, ntv, mtv, l);
        // pair reduce over kh
        if (khv == 1) {
          float* s = xg + (mtv * 2 + ntv) * 1024 + l * 16;
#pragma unroll
          for (int r = 0; r < 16; ++r) s[r] = acc[r];
        }
        __syncthreads();
        if (khv == 0) {
          const float* s = xg + (mtv * 2 + ntv) * 1024 + l * 16;
#pragma unroll
          for (int r = 0; r < 16; ++r) acc[r] += s[r];
        }
        __syncthreads();

        if (type == 1) {
          // write Wx1 partial for step t (consumed by H1 next phase)
          if (khv == 0) {
            float* pp = P + ((size_t)(t & 1) * 64 + i) * 4096;
#pragma unroll
            for (int r = 0; r < 16; ++r) {
              int row = (r & 3) + 8 * (r >> 2) + 4 * (l >> 5) + 32 * mtv;
              pp[row * 64 + ntv * 32 + (l & 31)] = acc[r];
            }
          }
        } else {
          // gates -> LDS [64row][68]
          if (khv == 0) {
#pragma unroll
            for (int r = 0; r < 16; ++r) {
              int row = (r & 3) + 8 * (r >> 2) + 4 * (l >> 5) + 32 * mtv;
              xg[row * 68 + ntv * 32 + (l & 31)] = acc[r];
            }
          }
          __syncthreads();
          // LSTM update: 2 cells/thread, cells = 16j x 64b
          unsigned short* dst = ((type == 0) ? h0f : h1f) + (size_t)(p & 1) * HSLOT;
#pragma unroll
          for (int q = 0; q < 2; ++q) {
            int id = tid * 2 + q;
            int jl = id >> 6, r = id & 63;
            int j = 16 * i + jl;
            int ntc = jl >> 3, jo = jl & 7;
            float gi_ = xg[r * 68 + ntc * 32 + jo];
            float gf_ = xg[r * 68 + ntc * 32 + 8 + jo];
            float gg_ = xg[r * 68 + ntc * 32 + 16 + jo];
            float go_ = xg[r * 68 + ntc * 32 + 24 + jo];
            if (type == 0) {
              int v = idx[r * Tn + t];
              const float* er = EW0 + (size_t)v * Gn + j;  // includes b0
              gi_ += er[0]; gf_ += er[Hn]; gg_ += er[2 * Hn]; go_ += er[3 * Hn];
            } else {
              const float* pr = P + ((size_t)(t & 1) * 64 + i) * 4096 + r * 64 + ntc * 32;
              gi_ += pr[jo] + bias[Gn + j];
              gf_ += pr[8 + jo] + bias[Gn + Hn + j];
              gg_ += pr[16 + jo] + bias[Gn + 2 * Hn + j];
              go_ += pr[24 + jo] + bias[Gn + 3 * Hn + j];
            }
            float c_ = cb[jl * 64 + r];
            float cn = sigf(gf_) * c_ + sigf(gi_) * tanh_(gg_);
            float hn = sigf(go_) * tanh_(cn);
            cb[jl * 64 + r] = cn;
            unsigned short hh = bf_hi(hn);
            unsigned short hl = bf_hi(hn - bf_f(hh));
            int ks = j >> 4, sub = j & 15;
            int lt = (r & 31) | ((sub >> 3) << 5), e = sub & 7, mtt = r >> 5;
            dst[(((size_t)ks * 2 + 0) * 2 + mtt) * 512 + lt * 8 + e] = hh;
            dst[(((size_t)ks * 2 + 1) * 2 + mtt) * 512 + lt * 8 + e] = hl;
          }
        }
      } else {
        // ---- out-projection: quad tree-reduce over kq, then direct store ----
        f32x16 acc = gemm_run<16>(Asrc, wlo, whi, ks0, 0, mtv, l);
        int kq = khv;
        if (kq >= 2) {
          float* s = xg + (mtv * 2 + (kq - 2)) * 1024 + l * 16;
#pragma unroll
          for (int r = 0; r < 16; ++r) s[r] = acc[r];
        }
        __syncthreads();
        if (kq < 2) {
          const float* s = xg + (mtv * 2 + kq) * 1024 + l * 16;
#pragma unroll
          for (int r = 0; r < 16; ++r) acc[r] += s[r];
        }
        __syncthreads();
        if (kq == 1) {
          float* s = xg + mtv * 1024 + l * 16;
#pragma unroll
          for (int r = 0; r < 16; ++r) s[r] = acc[r];
        }
        __syncthreads();
        if (kq == 0) {
          const float* s = xg + mtv * 1024 + l * 16;
#pragma unroll
          for (int r = 0; r < 16; ++r) acc[r] += s[r];
#pragma unroll
          for (int r = 0; r < 16; ++r) {
            int row = (r & 3) + 8 * (r >> 2) + 4 * (l >> 5) + 32 * mtv;
            out[((size_t)row * Tn + t) * Vn + 32 * i + (l & 31)] = acc[r];
          }
        }
      }
    }
    gridbar(cnt, flag, p);
  }
}

// =======================================================================
extern "C" void kernel_launch(void* const* d_in, const int* in_sizes, int n_in,
                              void* d_out, int out_size, void* d_ws, size_t ws_size,
                              hipStream_t stream) {
  const int* idx = (const int*)d_in[0];        // (B,T) int32
  const float* embed = (const float*)d_in[1];  // (V,H)
  const float* Wx = (const float*)d_in[2];     // (L,H,4H)
  const float* Wh = (const float*)d_in[3];     // (L,H,4H)
  const float* bias = (const float*)d_in[4];   // (L,4H)
  const float* Wout = (const float*)d_in[5];   // (H,V)
  float* out = (float*)d_out;                  // (B,T,V) fp32

  // workspace: EW0 2MB | h0f 512KB | h1f 512KB | P 2MB | barrier
  float* EW0 = (float*)d_ws;                               // 524288 f
  unsigned short* h0f = (unsigned short*)(EW0 + 524288);   // 2 slots x 131072 us
  unsigned short* h1f = h0f + 2 * HSLOT;
  float* P = (float*)(h1f + 2 * HSLOT);                    // 2 x 64 x 4096 f
  unsigned* bar = (unsigned*)(P + 524288);

  hipMemsetAsync(h0f, 0, (size_t)4 * HSLOT * 2, stream);   // h0f + h1f (1 MB)
  hipMemsetAsync(bar, 0, 1024, stream);                    // barrier state (every call!)

  ew0_kernel<<<dim3(Gn / 256, Vn / 8), 256, 0, stream>>>(embed, Wx, bias, EW0);

  hipFuncSetAttribute((const void*)persist_kernel,
                      hipFuncAttributeMaxDynamicSharedMemorySize, 152576);

  void* args[] = {(void*)&idx, (void*)&Wx, (void*)&Wh, (void*)&bias, (void*)&Wout,
                  (void*)&EW0, (void*)&h0f, (void*)&h1f, (void*)&P, (void*)&out,
                  (void*)&bar};
  hipLaunchCooperativeKernel((const void*)persist_kernel, dim3(NWG), dim3(512),
                             args, 152576, stream);

  (void)embed; (void)in_sizes; (void)n_in; (void)out_size; (void)ws_size;
}

// Round 4
// 32938.705 us; speedup vs baseline: 1.0616x; 1.0616x over previous
//
#include <hip/hip_runtime.h>
#include <math.h>

#define Hn 1024
#define Gn 4096   // 4*H
#define Bn 64
#define Tn 512
#define Vn 128
#define NWG 196
#define NPH 515       // phases: H0 t=p, X1 t=p-1, H1 t=p-2, C t=p-3
#define HSLOT 131072  // ushorts per h-fragment slot: 64ks x 2pl x 2mt x 64lane x 8e

typedef short bf16x8 __attribute__((ext_vector_type(8)));
typedef float f32x16 __attribute__((ext_vector_type(16)));

#define MFMA(a, b, c) __builtin_amdgcn_mfma_f32_32x32x16_bf16(a, b, c, 0, 0, 0)

// ---------------- numeric helpers (validated r2/r3) ----------------
__device__ __forceinline__ unsigned short bf_hi(float x) {
  unsigned u = __builtin_bit_cast(unsigned, x);
  return (unsigned short)((u + 0x7fffu + ((u >> 16) & 1u)) >> 16);  // RNE bf16
}
__device__ __forceinline__ float bf_f(unsigned short h) {
  unsigned u = ((unsigned)h) << 16;
  return __builtin_bit_cast(float, u);
}
__device__ __forceinline__ float sigf(float x) {
  float e = exp2f(x * -1.442695040888963f);
  return __fdividef(1.f, 1.f + e);
}
__device__ __forceinline__ float tanh_(float x) {
  x = fminf(fmaxf(x, -15.f), 15.f);
  float e = exp2f(x * -2.885390081777926f);
  return __fdividef(1.f - e, 1.f + e);
}

// ---------------- EW0 = embed @ Wx0 + b0 (V x G), fp32 (validated) ----------------
__global__ void ew0_kernel(const float* __restrict__ embed, const float* __restrict__ Wx0,
                           const float* __restrict__ bias, float* __restrict__ EW0) {
  int n = blockIdx.x * 256 + threadIdx.x;
  int vb = blockIdx.y * 8;
  float acc[8] = {0, 0, 0, 0, 0, 0, 0, 0};
  for (int k = 0; k < Hn; k++) {
    float w = Wx0[(size_t)k * Gn + n];
#pragma unroll
    for (int i = 0; i < 8; i++)
      acc[i] = fmaf(embed[(vb + i) * Hn + k], w, acc[i]);
  }
  float bb = bias[n];
#pragma unroll
  for (int i = 0; i < 8; i++)
    EW0[(size_t)(vb + i) * Gn + n] = acc[i] + bb;
}

// ---------------- grid barrier (validated r3 protocol) ----------------
__device__ __forceinline__ void gridbar(unsigned* cnt, unsigned* flag, int p) {
  __threadfence();
  __syncthreads();
  if (threadIdx.x == 0) {
    unsigned old = atomicAdd(cnt, 1u);
    if (old == (unsigned)(NWG - 1)) {
      atomicExch(cnt, 0u);
      __threadfence();
      atomicExch(flag, (unsigned)(p + 1));
    } else {
      while (atomicAdd(flag, 0u) < (unsigned)(p + 1)) __builtin_amdgcn_s_sleep(4);
    }
    __threadfence();
  }
  __syncthreads();
}

// ---------------- persistent phase-pipelined kernel ----------------
// blocks: [0,64) H0 (Wh0 + update), [64,128) X1 (Wx1 -> P), [128,192) H1 (Wh1 + P + update),
//         [192,196) C (out-proj).
// LDS: whi 131072B ([nt][64ks][lane][8] us; C-type uses nt=0 half) | xg 17408B | cb 4096B
__global__ __launch_bounds__(512, 2)
void persist_kernel(const int* __restrict__ idx,
                    const float* __restrict__ Wx, const float* __restrict__ Wh,
                    const float* __restrict__ bias, const float* __restrict__ Wout,
                    const float* __restrict__ EW0,
                    unsigned short* __restrict__ h0f, unsigned short* __restrict__ h1f,
                    unsigned short* __restrict__ wloPool,
                    float* __restrict__ P, float* __restrict__ out,
                    unsigned* __restrict__ bar) {
  extern __shared__ char smem[];
  unsigned short* whi = (unsigned short*)smem;          // 131072 B
  float* xg = (float*)(smem + 131072);                  // 17408 B: reduce [4tile][16r][64l] then gates [64][68]
  float* cb = (float*)(smem + 131072 + 17408);          // 4096 B: c-state [16jl][64b]

  const int b = blockIdx.x, tid = threadIdx.x;
  const int wv = tid >> 6, l = tid & 63;
  const int type = (b < 64) ? 0 : (b < 128) ? 1 : (b < 192) ? 2 : 3;
  const int i = b - ((type == 0) ? 0 : (type == 1) ? 64 : (type == 2) ? 128 : 192);
  const int mtv = wv & 1, khv = wv >> 1;                // khv in [0,4), 16 ks each
  unsigned short* wlo = wloPool + (size_t)b * 65536;

  // ---- one-time pack: hi -> LDS, lo -> private global slab (L2-local) ----
  {
    const int c32 = l & 31, o8 = (l >> 5) * 8;
    if (type < 3) {
      const float* Wsrc = (type == 0) ? Wh
                        : (type == 1) ? (Wx + (size_t)Hn * Gn)
                                      : (Wh + (size_t)Hn * Gn);
      for (int nt = 0; nt < 2; nt++) {
        int colv = (c32 >> 3) * Hn + 16 * i + nt * 8 + (c32 & 7);
        for (int kk = 0; kk < 8; kk++) {
          int ks = wv * 8 + kk;
          bf16x8 hv, lv;
#pragma unroll
          for (int e = 0; e < 8; e++) {
            float w = Wsrc[(size_t)(ks * 16 + o8 + e) * Gn + colv];
            unsigned short h = bf_hi(w);
            unsigned short lo = bf_hi(w - bf_f(h));
            hv[e] = (short)h; lv[e] = (short)lo;
          }
          size_t off = ((size_t)nt * 64 + ks) * 512 + (size_t)l * 8;
          *(bf16x8*)(whi + off) = hv;
          *(bf16x8*)(wlo + off) = lv;
        }
      }
    } else {
      int colv = 32 * i + c32;
      for (int kk = 0; kk < 8; kk++) {
        int ks = wv * 8 + kk;
        bf16x8 hv, lv;
#pragma unroll
        for (int e = 0; e < 8; e++) {
          float w = Wout[(size_t)(ks * 16 + o8 + e) * Vn + colv];
          unsigned short h = bf_hi(w);
          unsigned short lo = bf_hi(w - bf_f(h));
          hv[e] = (short)h; lv[e] = (short)lo;
        }
        size_t off = (size_t)ks * 512 + (size_t)l * 8;
        *(bf16x8*)(whi + off) = hv;
        *(bf16x8*)(wlo + off) = lv;
      }
    }
  }
  for (int q = tid; q < 1024; q += 512) cb[q] = 0.f;
  __syncthreads();

  unsigned* cnt = bar;
  unsigned* flag = bar + 64;

  // ---- phase loop ----
  for (int p = 0; p < NPH; ++p) {
    const int sA = (p + 1) & 1;
    int t; bool active;
    if (type == 0)      { t = p;     active = (t < Tn); }
    else if (type == 1) { t = p - 1; active = (t >= 0 && t < Tn); }
    else if (type == 2) { t = p - 2; active = (t >= 0 && t < Tn); }
    else                { t = p - 3; active = (t >= 0 && t < Tn); }

    if (active) {
      const unsigned short* A = ((type <= 1) ? h0f : h1f) + (size_t)sA * HSLOT;
      f32x16 acc0 = {}, acc1 = {};
      const int ks0 = khv * 16;
#pragma unroll
      for (int k2 = 0; k2 < 16; ++k2) {
        const int ks = ks0 + k2;
        const unsigned short* ap = A + ((size_t)ks * 4 + mtv) * 512 + (size_t)l * 8;
        bf16x8 ahi = *(const bf16x8*)ap;             // pl=0
        bf16x8 alo = *(const bf16x8*)(ap + 1024);    // pl=1
        size_t w0 = (size_t)ks * 512 + (size_t)l * 8;
        bf16x8 bh0 = *(const bf16x8*)(whi + w0);
        bf16x8 bl0 = *(const bf16x8*)(wlo + w0);
        acc0 = MFMA(ahi, bh0, acc0);
        acc0 = MFMA(alo, bh0, acc0);
        acc0 = MFMA(ahi, bl0, acc0);
        if (type < 3) {
          bf16x8 bh1 = *(const bf16x8*)(whi + w0 + 32768);
          bf16x8 bl1 = *(const bf16x8*)(wlo + w0 + 32768);
          acc1 = MFMA(ahi, bh1, acc1);
          acc1 = MFMA(alo, bh1, acc1);
          acc1 = MFMA(ahi, bl1, acc1);
        }
      }

      // ---- 4-way kh reduce, conflict-free [tile][r][lane] layout ----
#pragma unroll
      for (int rd = 1; rd < 4; ++rd) {
        if (khv == rd) {
          float* s0 = xg + (mtv * 2 + 0) * 1024 + l;
          float* s1 = xg + (mtv * 2 + 1) * 1024 + l;
#pragma unroll
          for (int r = 0; r < 16; ++r) { s0[r * 64] = acc0[r]; s1[r * 64] = acc1[r]; }
        }
        __syncthreads();
        if (khv == 0) {
          const float* s0 = xg + (mtv * 2 + 0) * 1024 + l;
          const float* s1 = xg + (mtv * 2 + 1) * 1024 + l;
#pragma unroll
          for (int r = 0; r < 16; ++r) { acc0[r] += s0[r * 64]; acc1[r] += s1[r * 64]; }
        }
        __syncthreads();
      }

      if (type == 1) {
        if (khv == 0) {
          float* pp = P + ((size_t)(t & 1) * 64 + i) * 4096;
#pragma unroll
          for (int r = 0; r < 16; ++r) {
            int row = (r & 3) + 8 * (r >> 2) + 4 * (l >> 5) + 32 * mtv;
            pp[row * 64 + (l & 31)] = acc0[r];
            pp[row * 64 + 32 + (l & 31)] = acc1[r];
          }
        }
      } else if (type == 3) {
        if (khv == 0) {
#pragma unroll
          for (int r = 0; r < 16; ++r) {
            int row = (r & 3) + 8 * (r >> 2) + 4 * (l >> 5) + 32 * mtv;
            out[((size_t)row * Tn + t) * Vn + 32 * i + (l & 31)] = acc0[r];
          }
        }
      } else {
        // ---- type 0/2: gates -> LDS, LSTM update (validated r3 mappings) ----
        if (khv == 0) {
#pragma unroll
          for (int r = 0; r < 16; ++r) {
            int row = (r & 3) + 8 * (r >> 2) + 4 * (l >> 5) + 32 * mtv;
            xg[row * 68 + (l & 31)] = acc0[r];
            xg[row * 68 + 32 + (l & 31)] = acc1[r];
          }
        }
        __syncthreads();
        unsigned short* dst = ((type == 0) ? h0f : h1f) + (size_t)(p & 1) * HSLOT;
#pragma unroll
        for (int q = 0; q < 2; ++q) {
          int id = tid * 2 + q;
          int jl = id >> 6, r = id & 63;
          int j = 16 * i + jl;
          int ntc = jl >> 3, jo = jl & 7;
          float gi_ = xg[r * 68 + ntc * 32 + jo];
          float gf_ = xg[r * 68 + ntc * 32 + 8 + jo];
          float gg_ = xg[r * 68 + ntc * 32 + 16 + jo];
          float go_ = xg[r * 68 + ntc * 32 + 24 + jo];
          if (type == 0) {
            int v = idx[r * Tn + t];
            const float* er = EW0 + (size_t)v * Gn + j;  // includes b0
            gi_ += er[0]; gf_ += er[Hn]; gg_ += er[2 * Hn]; go_ += er[3 * Hn];
          } else {
            const float* pr = P + ((size_t)(t & 1) * 64 + i) * 4096 + r * 64 + ntc * 32;
            gi_ += pr[jo] + bias[Gn + j];
            gf_ += pr[8 + jo] + bias[Gn + Hn + j];
            gg_ += pr[16 + jo] + bias[Gn + 2 * Hn + j];
            go_ += pr[24 + jo] + bias[Gn + 3 * Hn + j];
          }
          float c_ = cb[jl * 64 + r];
          float cn = sigf(gf_) * c_ + sigf(gi_) * tanh_(gg_);
          float hn = sigf(go_) * tanh_(cn);
          cb[jl * 64 + r] = cn;
          unsigned short hh = bf_hi(hn);
          unsigned short hl = bf_hi(hn - bf_f(hh));
          int ks = j >> 4, sub = j & 15;
          int lt = (r & 31) | ((sub >> 3) << 5);
          int e = sub & 7, mtt = r >> 5;
          dst[((size_t)ks * 4 + mtt) * 512 + (size_t)lt * 8 + e] = hh;
          dst[((size_t)ks * 4 + 2 + mtt) * 512 + (size_t)lt * 8 + e] = hl;
        }
      }
    }
    gridbar(cnt, flag, p);
  }
}

// =======================================================================
extern "C" void kernel_launch(void* const* d_in, const int* in_sizes, int n_in,
                              void* d_out, int out_size, void* d_ws, size_t ws_size,
                              hipStream_t stream) {
  const int* idx = (const int*)d_in[0];        // (B,T) int32
  const float* embed = (const float*)d_in[1];  // (V,H)
  const float* Wx = (const float*)d_in[2];     // (L,H,4H)
  const float* Wh = (const float*)d_in[3];     // (L,H,4H)
  const float* bias = (const float*)d_in[4];   // (L,4H)
  const float* Wout = (const float*)d_in[5];   // (H,V)
  float* out = (float*)d_out;                  // (B,T,V) fp32

  // workspace: EW0 2MB | h0f 512KB | h1f 512KB | P 2MB | wlo 25.7MB | bar
  float* EW0 = (float*)d_ws;                               // 524288 f
  unsigned short* h0f = (unsigned short*)(EW0 + 524288);   // 2 x HSLOT us
  unsigned short* h1f = h0f + 2 * HSLOT;
  float* P = (float*)(h1f + 2 * HSLOT);                    // 2 x 64 x 4096 f
  unsigned short* wloPool = (unsigned short*)(P + 524288); // NWG x 65536 us
  unsigned* bar = (unsigned*)(wloPool + (size_t)NWG * 65536);

  hipMemsetAsync(h0f, 0, (size_t)4 * HSLOT * 2, stream);   // h0f + h1f
  hipMemsetAsync(bar, 0, 1024, stream);                    // barrier state (every call)

  ew0_kernel<<<dim3(Gn / 256, Vn / 8), 256, 0, stream>>>(embed, Wx, bias, EW0);

  hipFuncSetAttribute((const void*)persist_kernel,
                      hipFuncAttributeMaxDynamicSharedMemorySize, 152576);

  void* args[] = {(void*)&idx, (void*)&Wx, (void*)&Wh, (void*)&bias, (void*)&Wout,
                  (void*)&EW0, (void*)&h0f, (void*)&h1f, (void*)&wloPool,
                  (void*)&P, (void*)&out, (void*)&bar};
  hipLaunchCooperativeKernel((const void*)persist_kernel, dim3(NWG), dim3(512),
                             args, 152576, stream);

  (void)embed; (void)in_sizes; (void)n_in; (void)out_size; (void)ws_size;
}